// Round 2
// 1426.132 us; speedup vs baseline: 1.2527x; 1.2527x over previous
//
#include <hip/hip_runtime.h>
#include <hip/hip_bf16.h>

#define N_ROWS 512
#define DIM    2048
#define P_ROWS 100000

#define BM 128
#define BN 128
#define BK 32
#define KT (DIM / BK)          // 64 k-iterations
#define PTILES ((P_ROWS + BN - 1) / BN)   // 782
#define PT8 (((PTILES + 7) / 8) * 8)      // 784 (XCD-affine grid rounding)

typedef __attribute__((ext_vector_type(8))) short short8;   // 8 bf16 (4 VGPRs)
typedef __attribute__((ext_vector_type(4))) float floatx4;  // 4 fp32 acc

// ws layout (float / uint slots):
//   [0, 512)        xx[i]   = ||x_i||^2                  (float)
//   [512, 1024)     ap[i]   = d2(i, labels[i]) exact fp32 (float)
//   [1024, 1536)    gmin[i] = min d2 over j != label      (uint bits of nonneg float)
//   [1536, 101536)  yy[j]   = ||f_j||^2                   (float)  [bf16 path only]
// byte offsets (bf16 path only):
//   [1 MiB, 3 MiB)            x_bf16   [512][2048] bf16
//   [4 MiB, 4 MiB + 390.6 MiB) feats_bf16 [100000][2048] bf16
#define WS_YY   1536
#define XB_OFF  ((size_t)1 << 20)
#define FB_OFF  ((size_t)4 << 20)
#define WS_NEEDED (FB_OFF + (size_t)P_ROWS * DIM * 2)

// RNE pack of two fp32 into one dword of two bf16 (a -> low half)
__device__ inline unsigned pack2_bf16(float a, float b) {
    unsigned ua = __float_as_uint(a), ub = __float_as_uint(b);
    ua += 0x7FFFu + ((ua >> 16) & 1u);
    ub += 0x7FFFu + ((ub >> 16) & 1u);
    return (ua >> 16) | (ub & 0xFFFF0000u);
}

// async global->LDS, 16B per lane; LDS dst = wave-uniform base + lane*16
__device__ __forceinline__ void gload16(const void* g, void* l) {
    __builtin_amdgcn_global_load_lds(
        (const __attribute__((address_space(1))) void*)g,
        (__attribute__((address_space(3))) void*)l,
        16, 0, 0);
}

// ---------------------------------------------------------------------------
// Kernel A: per-row fp32 stats: xx, exact d2 to the label slot, init gmin=+inf.
// Optionally also emits the bf16 copy of the x row (xb != nullptr).
// ---------------------------------------------------------------------------
__global__ __launch_bounds__(256) void rowstats_kernel(
    const float* __restrict__ x, const float* __restrict__ feats,
    const int* __restrict__ labels, float* __restrict__ ws,
    unsigned short* __restrict__ xb)
{
    const int i = blockIdx.x;
    const int t = threadIdx.x;
    const int lab = labels[i];
    const float* xr = x + (size_t)i * DIM + t * 8;
    const float* fr = feats + (size_t)lab * DIM + t * 8;
    const float4 a0 = *reinterpret_cast<const float4*>(xr);
    const float4 a1 = *reinterpret_cast<const float4*>(xr + 4);
    const float4 b0 = *reinterpret_cast<const float4*>(fr);
    const float4 b1 = *reinterpret_cast<const float4*>(fr + 4);
    float s1 = a0.x*a0.x + a0.y*a0.y + a0.z*a0.z + a0.w*a0.w
             + a1.x*a1.x + a1.y*a1.y + a1.z*a1.z + a1.w*a1.w;
    float s2 = b0.x*b0.x + b0.y*b0.y + b0.z*b0.z + b0.w*b0.w
             + b1.x*b1.x + b1.y*b1.y + b1.z*b1.z + b1.w*b1.w;
    float s3 = a0.x*b0.x + a0.y*b0.y + a0.z*b0.z + a0.w*b0.w
             + a1.x*b1.x + a1.y*b1.y + a1.z*b1.z + a1.w*b1.w;
    if (xb) {
        uint4 pk;
        pk.x = pack2_bf16(a0.x, a0.y); pk.y = pack2_bf16(a0.z, a0.w);
        pk.z = pack2_bf16(a1.x, a1.y); pk.w = pack2_bf16(a1.z, a1.w);
        *reinterpret_cast<uint4*>(&xb[(size_t)i * DIM + t * 8]) = pk;
    }
    for (int off = 32; off; off >>= 1) {
        s1 += __shfl_down(s1, off);
        s2 += __shfl_down(s2, off);
        s3 += __shfl_down(s3, off);
    }
    __shared__ float r1[4], r2[4], r3[4];
    const int w = t >> 6;
    if ((t & 63) == 0) { r1[w] = s1; r2[w] = s2; r3[w] = s3; }
    __syncthreads();
    if (t == 0) {
        float q1 = r1[0] + r1[1] + r1[2] + r1[3];
        float q2 = r2[0] + r2[1] + r2[2] + r2[3];
        float q3 = r3[0] + r3[1] + r3[2] + r3[3];
        ws[i] = q1;                               // xx
        ws[N_ROWS + i] = q1 + q2 - 2.0f * q3;     // ap d2 (exact fp32)
        ((unsigned*)ws)[2 * N_ROWS + i] = 0x7F800000u;  // +inf bits
    }
}

// ---------------------------------------------------------------------------
// Kernel A2: one-shot fp32 -> bf16 conversion of feats + fused ||f_j||^2.
// 1 row per block, 8 contiguous elems per thread. Streaming, HBM-bound.
// ---------------------------------------------------------------------------
__global__ __launch_bounds__(256) void convert_feats_kernel(
    const float* __restrict__ feats, float* __restrict__ ws,
    unsigned short* __restrict__ fbm)
{
    const int j = blockIdx.x;
    const int t = threadIdx.x;
    const float* fr = feats + (size_t)j * DIM + t * 8;
    const float4 v0 = *reinterpret_cast<const float4*>(fr);
    const float4 v1 = *reinterpret_cast<const float4*>(fr + 4);
    uint4 pk;
    pk.x = pack2_bf16(v0.x, v0.y); pk.y = pack2_bf16(v0.z, v0.w);
    pk.z = pack2_bf16(v1.x, v1.y); pk.w = pack2_bf16(v1.z, v1.w);
    *reinterpret_cast<uint4*>(&fbm[(size_t)j * DIM + t * 8]) = pk;
    float ss = v0.x*v0.x + v0.y*v0.y + v0.z*v0.z + v0.w*v0.w
             + v1.x*v1.x + v1.y*v1.y + v1.z*v1.z + v1.w*v1.w;
    for (int off = 32; off; off >>= 1) ss += __shfl_down(ss, off);
    __shared__ float r[4];
    if ((t & 63) == 0) r[t >> 6] = ss;
    __syncthreads();
    if (t == 0) ws[WS_YY + j] = r[0] + r[1] + r[2] + r[3];
}

// ---------------------------------------------------------------------------
// Kernel B (bf16 path): m97-structure MFMA GEMM on pre-converted bf16 with
// global_load_lds width-16 staging, linear LDS, fused masked-min epilogue.
// XCD-affine bid mapping: the 4 m-tiles of one p-tile are bids spaced 8 apart
// -> same XCD (bid%8) -> B-tile fetched once into that XCD's L2.
// ---------------------------------------------------------------------------
__global__ __launch_bounds__(256) void gemm_min_bf16_kernel(
    const unsigned short* __restrict__ xb,
    const unsigned short* __restrict__ fbm,
    const int* __restrict__ labels, float* __restrict__ ws)
{
    __shared__ unsigned short As[BM * BK];   // 8 KiB, row-major [128][32]
    __shared__ unsigned short Bs[BN * BK];   // 8 KiB
    __shared__ float xx_s[BM];
    __shared__ float yy_s[BN];
    __shared__ int   lab_s[BM];

    const int tid = threadIdx.x;
    const int bid = blockIdx.x;
    const int pt  = (bid >> 5) * 8 + (bid & 7);   // p-tile
    const int mt  = (bid >> 3) & 3;               // m-tile
    if (pt >= PTILES) return;
    const int m0 = mt * BM;
    const int p0 = pt * BN;

    if (tid < 128) {
        xx_s[tid]  = ws[m0 + tid];
        lab_s[tid] = labels[m0 + tid];
        const int jg = p0 + tid;
        yy_s[tid]  = (jg < P_ROWS) ? ws[WS_YY + jg] : 0.f;
    }

    // staging geometry: tile = 8 KiB = 8 chunks of 1 KiB; wave w owns chunks
    // {2w, 2w+1}. One gload16 per chunk: lane l -> row c*16 + (l>>2),
    // 16 B at byte (l&3)*16 within the 64 B row. LDS written linearly.
    const int lane = tid & 63;
    const int wid  = tid >> 6;
    const int srow  = lane >> 2;
    const int scolb = (lane & 3) << 4;
    const int c0 = 2 * wid, c1 = 2 * wid + 1;
    const size_t rowb = (size_t)DIM * 2;   // 4096 B per bf16 row

    const char* gA0 = (const char*)xb + (size_t)(m0 + c0 * 16 + srow) * rowb + scolb;
    const char* gA1 = (const char*)xb + (size_t)(m0 + c1 * 16 + srow) * rowb + scolb;
    int br0 = p0 + c0 * 16 + srow; br0 = br0 < P_ROWS ? br0 : P_ROWS - 1;
    int br1 = p0 + c1 * 16 + srow; br1 = br1 < P_ROWS ? br1 : P_ROWS - 1;
    const char* gB0 = (const char*)fbm + (size_t)br0 * rowb + scolb;
    const char* gB1 = (const char*)fbm + (size_t)br1 * rowb + scolb;
    unsigned short* lA0 = As + c0 * 512;   // 512 shorts = 1 KiB chunk
    unsigned short* lA1 = As + c1 * 512;
    unsigned short* lB0 = Bs + c0 * 512;
    unsigned short* lB1 = Bs + c1 * 512;

    const int wm = (wid & 1) * 64;
    const int wn = (wid >> 1) * 64;
    const int cq = lane >> 4;
    const int cc = lane & 15;

    floatx4 acc[4][4];
    for (int mi = 0; mi < 4; ++mi)
        for (int ni = 0; ni < 4; ++ni)
            acc[mi][ni] = (floatx4){0.f, 0.f, 0.f, 0.f};

    for (int kt = 0; kt < KT; ++kt) {
        const int kb = kt * (BK * 2);   // 64 B per k-step
        __syncthreads();                 // prev iter frag reads done
        gload16(gA0 + kb, lA0);
        gload16(gA1 + kb, lA1);
        gload16(gB0 + kb, lB0);
        gload16(gB1 + kb, lB1);
        __syncthreads();                 // compiler drains vmcnt before barrier
        short8 bfr[4];
        #pragma unroll
        for (int ni = 0; ni < 4; ++ni)
            bfr[ni] = *(const short8*)&Bs[(wn + ni * 16 + cc) * BK + cq * 8];
        #pragma unroll
        for (int mi = 0; mi < 4; ++mi) {
            const short8 afr = *(const short8*)&As[(wm + mi * 16 + cc) * BK + cq * 8];
            #pragma unroll
            for (int ni = 0; ni < 4; ++ni)
                acc[mi][ni] = __builtin_amdgcn_mfma_f32_16x16x32_bf16(
                    afr, bfr[ni], acc[mi][ni], 0, 0, 0);
        }
    }

    // epilogue: d2 = xx + yy - 2*dot; mask label & OOB; per-row min -> atomicMin
    unsigned* gmin = (unsigned*)ws + 2 * N_ROWS;
    #pragma unroll
    for (int mi = 0; mi < 4; ++mi) {
        #pragma unroll
        for (int rg = 0; rg < 4; ++rg) {
            const int li  = wm + mi * 16 + cq * 4 + rg;   // local row (C/D layout)
            const float xxv = xx_s[li];
            const int   lv  = lab_s[li];
            float vmin = __uint_as_float(0x7F800000u);    // +inf
            #pragma unroll
            for (int ni = 0; ni < 4; ++ni) {
                const int jl = wn + ni * 16 + cc;
                const int jg = p0 + jl;
                float d2 = xxv + yy_s[jl] - 2.0f * acc[mi][ni][rg];
                if (jg >= P_ROWS || jg == lv) d2 = __uint_as_float(0x7F800000u);
                vmin = fminf(vmin, d2);
            }
            for (int off = 1; off <= 8; off <<= 1)
                vmin = fminf(vmin, __shfl_xor(vmin, off));
            if (cc == 0) {
                vmin = fmaxf(vmin, 0.0f);   // nonneg => uint order == float order
                atomicMin(&gmin[m0 + li], __float_as_uint(vmin));
            }
        }
    }
}

// ---------------------------------------------------------------------------
// Kernel B-fallback (small ws): previous verified kernel, unchanged.
// ---------------------------------------------------------------------------
#define LDSTRIDE 40   // bf16 elems per LDS row (32 + 8 pad; 80 B, 16B-aligned)

__global__ __launch_bounds__(256) void gemm_min_kernel(
    const float* __restrict__ x, const float* __restrict__ feats,
    const int* __restrict__ labels, float* __restrict__ ws)
{
    __shared__ unsigned short As[BM * LDSTRIDE];
    __shared__ unsigned short Bs[BN * LDSTRIDE];
    __shared__ float ss_lds[128 * 8];
    __shared__ float xx_s[128];
    __shared__ int   lab_s[128];
    __shared__ float yy_s[128];

    const int tid = threadIdx.x;
    const int bid = blockIdx.x;
    const int mt  = bid & 3;
    const int pt  = bid >> 2;
    const int m0  = mt * BM;
    const int p0  = pt * BN;

    if (tid < 128) {
        xx_s[tid]  = ws[m0 + tid];
        lab_s[tid] = labels[m0 + tid];
    }

    const int jb = tid >> 3;
    const int c8 = tid & 7;
    const int c0 = c8 * 4;

    bool bvalid[4];
    const float* aptr[4];
    const float* bptr[4];
    for (int r = 0; r < 4; ++r) {
        const int arow = m0 + r * 32 + jb;
        const int brow = p0 + r * 32 + jb;
        bvalid[r] = (brow < P_ROWS);
        aptr[r] = x + (size_t)arow * DIM + c0;
        bptr[r] = feats + (size_t)(bvalid[r] ? brow : 0) * DIM + c0;
    }

    const int lane = tid & 63;
    const int wid  = tid >> 6;
    const int wm   = (wid & 1) * 64;
    const int wn   = (wid >> 1) * 64;
    const int cq   = lane >> 4;
    const int cc   = lane & 15;

    floatx4 acc[4][4];
    for (int mi = 0; mi < 4; ++mi)
        for (int ni = 0; ni < 4; ++ni)
            acc[mi][ni] = (floatx4){0.f, 0.f, 0.f, 0.f};
    float ssacc[4] = {0.f, 0.f, 0.f, 0.f};

    float4 ra[4], rb[4];
    for (int r = 0; r < 4; ++r) {
        ra[r] = *reinterpret_cast<const float4*>(aptr[r]);
        rb[r] = bvalid[r] ? *reinterpret_cast<const float4*>(bptr[r])
                          : make_float4(0.f, 0.f, 0.f, 0.f);
    }

    for (int kt = 0; kt < KT; ++kt) {
        __syncthreads();
        for (int r = 0; r < 4; ++r) {
            const int base = (r * 32 + jb) * LDSTRIDE + c0;
            *(uint2*)&As[base] = make_uint2(pack2_bf16(ra[r].x, ra[r].y),
                                            pack2_bf16(ra[r].z, ra[r].w));
            *(uint2*)&Bs[base] = make_uint2(pack2_bf16(rb[r].x, rb[r].y),
                                            pack2_bf16(rb[r].z, rb[r].w));
            ssacc[r] += rb[r].x * rb[r].x + rb[r].y * rb[r].y
                      + rb[r].z * rb[r].z + rb[r].w * rb[r].w;
        }
        if (kt + 1 < KT) {
            const int koff = (kt + 1) * BK;
            for (int r = 0; r < 4; ++r) {
                ra[r] = *reinterpret_cast<const float4*>(aptr[r] + koff);
                rb[r] = bvalid[r] ? *reinterpret_cast<const float4*>(bptr[r] + koff)
                                  : make_float4(0.f, 0.f, 0.f, 0.f);
            }
        }
        __syncthreads();
        short8 bfr[4];
        for (int ni = 0; ni < 4; ++ni)
            bfr[ni] = *(const short8*)&Bs[(wn + ni * 16 + cc) * LDSTRIDE + cq * 8];
        for (int mi = 0; mi < 4; ++mi) {
            const short8 afr = *(const short8*)&As[(wm + mi * 16 + cc) * LDSTRIDE + cq * 8];
            for (int ni = 0; ni < 4; ++ni)
                acc[mi][ni] = __builtin_amdgcn_mfma_f32_16x16x32_bf16(
                    afr, bfr[ni], acc[mi][ni], 0, 0, 0);
        }
    }

    __syncthreads();
    for (int r = 0; r < 4; ++r)
        ss_lds[(r * 32 + jb) * 8 + c8] = ssacc[r];
    __syncthreads();
    if (tid < 128) {
        float s = 0.f;
        for (int c = 0; c < 8; ++c) s += ss_lds[tid * 8 + c];
        yy_s[tid] = s;
    }
    __syncthreads();

    unsigned* gmin = (unsigned*)ws + 2 * N_ROWS;
    for (int mi = 0; mi < 4; ++mi) {
        for (int rg = 0; rg < 4; ++rg) {
            const int li  = wm + mi * 16 + cq * 4 + rg;
            const float xxv = xx_s[li];
            const int   lv  = lab_s[li];
            float vmin = __uint_as_float(0x7F800000u);
            for (int ni = 0; ni < 4; ++ni) {
                const int jl = wn + ni * 16 + cc;
                const int jg = p0 + jl;
                float d2 = xxv + yy_s[jl] - 2.0f * acc[mi][ni][rg];
                if (jg >= P_ROWS || jg == lv) d2 = __uint_as_float(0x7F800000u);
                vmin = fminf(vmin, d2);
            }
            for (int off = 1; off <= 8; off <<= 1)
                vmin = fminf(vmin, __shfl_xor(vmin, off));
            if (cc == 0) {
                vmin = fmaxf(vmin, 0.0f);
                atomicMin(&gmin[m0 + li], __float_as_uint(vmin));
            }
        }
    }
}

// ---------------------------------------------------------------------------
// Kernel C: loss = mean(softplus(ap - an))
// ---------------------------------------------------------------------------
__global__ __launch_bounds__(512) void loss_kernel(
    const float* __restrict__ ws, float* __restrict__ out)
{
    const int t = threadIdx.x;
    const float ap2 = ws[N_ROWS + t];
    const float an2 = __uint_as_float(((const unsigned*)ws)[2 * N_ROWS + t]);
    const float ap = sqrtf(fmaxf(ap2, 1e-12f));
    const float an = sqrtf(fmaxf(an2, 1e-12f));
    const float z  = ap - an;
    float sp = fmaxf(z, 0.0f) + log1pf(expf(-fabsf(z)));
    for (int off = 32; off; off >>= 1) sp += __shfl_down(sp, off);
    __shared__ float r[8];
    if ((t & 63) == 0) r[t >> 6] = sp;
    __syncthreads();
    if (t == 0) {
        float s = 0.f;
        for (int w = 0; w < 8; ++w) s += r[w];
        out[0] = s / (float)N_ROWS;
    }
}

extern "C" void kernel_launch(void* const* d_in, const int* in_sizes, int n_in,
                              void* d_out, int out_size, void* d_ws, size_t ws_size,
                              hipStream_t stream) {
    const float* x      = (const float*)d_in[0];
    const float* feats  = (const float*)d_in[1];
    const int*   labels = (const int*)d_in[2];
    float* ws  = (float*)d_ws;
    float* out = (float*)d_out;

    if (ws_size >= WS_NEEDED) {
        unsigned short* xb  = (unsigned short*)((char*)d_ws + XB_OFF);
        unsigned short* fbm = (unsigned short*)((char*)d_ws + FB_OFF);
        rowstats_kernel<<<N_ROWS, 256, 0, stream>>>(x, feats, labels, ws, xb);
        convert_feats_kernel<<<P_ROWS, 256, 0, stream>>>(feats, ws, fbm);
        gemm_min_bf16_kernel<<<4 * PT8, 256, 0, stream>>>(xb, fbm, labels, ws);
        loss_kernel<<<1, 512, 0, stream>>>(ws, out);
    } else {
        rowstats_kernel<<<N_ROWS, 256, 0, stream>>>(x, feats, labels, ws, nullptr);
        gemm_min_kernel<<<4 * PTILES, 256, 0, stream>>>(x, feats, labels, ws);
        loss_kernel<<<1, 512, 0, stream>>>(ws, out);
    }
}